// Round 1
// baseline (527.212 us; speedup 1.0000x reference)
//
#include <hip/hip_runtime.h>
#include <hip/hip_bf16.h>

#define B_   2
#define S_   2048
#define D_   2048
#define H_   32
#define HKV_ 8
#define HD_  64
// G = H/HKV = 4

using bf16 = __hip_bfloat16;
typedef __bf16 bf16x8 __attribute__((ext_vector_type(8)));
typedef float  floatx4 __attribute__((ext_vector_type(4)));

__device__ inline void async16(const void* g, void* l) {
  __builtin_amdgcn_global_load_lds(
      (const __attribute__((address_space(1))) void*)g,
      (__attribute__((address_space(3))) void*)l, 16, 0, 0);
}

__device__ inline void store_val(bf16* p, float v)  { *p = __float2bfloat16(v); }
__device__ inline void store_val(float* p, float v) { *p = v; }

// -------------------- fp32 -> bf16 conversion, 8 elems/thread --------------
__global__ void f2b8(const float* __restrict__ in, bf16* __restrict__ out, int n8) {
  int i = blockIdx.x * blockDim.x + threadIdx.x;
  if (i >= n8) return;
  float4 a  = ((const float4*)in)[2 * i];
  float4 b2 = ((const float4*)in)[2 * i + 1];
  alignas(16) bf16 t[8];
  t[0] = __float2bfloat16(a.x);  t[1] = __float2bfloat16(a.y);
  t[2] = __float2bfloat16(a.z);  t[3] = __float2bfloat16(a.w);
  t[4] = __float2bfloat16(b2.x); t[5] = __float2bfloat16(b2.y);
  t[6] = __float2bfloat16(b2.z); t[7] = __float2bfloat16(b2.w);
  ((uint4*)out)[i] = *(const uint4*)t;
}

// -------------------- GEMM: C = A * B^T + bias ------------------------------
// A: (M,K) bf16 row-major; B: (N,K) bf16 row-major; bias: (N) fp32.
// TRANS=false: C[row*N+col]; TRANS=true: C[col*M+row] (i.e. stores C^T).
// 128x128 tile, BK=32, 256 threads (4 waves as 2x2 of 64x64).
template <typename OutT, bool TRANS>
__global__ __launch_bounds__(256, 2)
void gemm_bt(const bf16* __restrict__ A, const bf16* __restrict__ Bm,
             const float* __restrict__ bias, OutT* __restrict__ C,
             int M, int N, int K) {
  __shared__ bf16 As[128 * 32];
  __shared__ bf16 Bs[128 * 32];
  const int tid  = threadIdx.x;
  const int wid  = tid >> 6, lane = tid & 63;
  const int lm   = lane & 15, quad = lane >> 4;
  const int wm   = (wid >> 1) * 64, wn = (wid & 1) * 64;
  const int bm   = blockIdx.y, bn = blockIdx.x;

  const bf16* Ag = A  + (size_t)bm * 128 * K;
  const bf16* Bg = Bm + (size_t)bn * 128 * K;

  floatx4 acc[4][4] = {};

  // staging: thread t stages 16B chunks at LDS linear t*8 (+2048 per chunk)
  const int l0 = tid * 8;
  const int r0 = l0 >> 5, c0 = l0 & 31;   // chunk0: rows 0..63
  const int r1 = r0 + 64;                 // chunk1: rows 64..127, same col

  for (int k0 = 0; k0 < K; k0 += 32) {
    async16(Ag + (size_t)r0 * K + k0 + c0, &As[l0]);
    async16(Ag + (size_t)r1 * K + k0 + c0, &As[l0 + 2048]);
    async16(Bg + (size_t)r0 * K + k0 + c0, &Bs[l0]);
    async16(Bg + (size_t)r1 * K + k0 + c0, &Bs[l0 + 2048]);
    asm volatile("s_waitcnt vmcnt(0)" ::: "memory");
    __syncthreads();

    bf16x8 aF[4], bF[4];
#pragma unroll
    for (int mi = 0; mi < 4; ++mi)
      aF[mi] = *(const bf16x8*)&As[(wm + mi * 16 + lm) * 32 + quad * 8];
#pragma unroll
    for (int ni = 0; ni < 4; ++ni)
      bF[ni] = *(const bf16x8*)&Bs[(wn + ni * 16 + lm) * 32 + quad * 8];
#pragma unroll
    for (int mi = 0; mi < 4; ++mi)
#pragma unroll
      for (int ni = 0; ni < 4; ++ni)
        acc[mi][ni] = __builtin_amdgcn_mfma_f32_16x16x32_bf16(aF[mi], bF[ni], acc[mi][ni], 0, 0, 0);
    __syncthreads();
  }

  // epilogue: C/D layout col=lane&15, row=quad*4+reg
#pragma unroll
  for (int ni = 0; ni < 4; ++ni) {
    const int col = bn * 128 + wn + ni * 16 + lm;
    const float bv = bias[col];
#pragma unroll
    for (int mi = 0; mi < 4; ++mi) {
      const int row0 = bm * 128 + wm + mi * 16 + quad * 4;
#pragma unroll
      for (int r = 0; r < 4; ++r) {
        float v = acc[mi][ni][r] + bv;
        if constexpr (TRANS)
          store_val(&C[(size_t)col * M + row0 + r], v);
        else
          store_val(&C[(size_t)(row0 + r) * N + col], v);
      }
    }
  }
}

// -------------------- causal GQA flash attention ----------------------------
// Q: (B*S, H*HD) bf16 ; K: (B*S, HKV*HD) bf16 ; VT: (HKV*HD, B*S) bf16
// O: (B*S, H*HD) bf16. Block = 256 thr = 4 waves; block does 64 q-rows of one
// (b,h); wave w handles q rows [w*16, w*16+16). KV tiles of 64.
__global__ __launch_bounds__(256, 2)
void attn_kernel(const bf16* __restrict__ Q, const bf16* __restrict__ K,
                 const bf16* __restrict__ VT, bf16* __restrict__ O) {
  const int qt = blockIdx.x, h = blockIdx.y, b = blockIdx.z;
  const int kvh = h >> 2;  // G = 4
  const int tid = threadIdx.x;
  const int wid = tid >> 6, lane = tid & 63;
  const int lm = lane & 15, quad = lane >> 4;

  // split layouts: [k-half][row][32] so ds_read_b128 has stride-32 bank spread
  __shared__ bf16 Ks[2 * 64 * 32];   // (kv, hd) : half = hd/32
  __shared__ bf16 Vs[2 * 64 * 32];   // (hd, kv) : half = kv/32
  __shared__ bf16 Ps[4][2 * 16 * 32];

  const int q0 = qt * 64;
  const int qrow_w = q0 + wid * 16;
  const size_t qg = ((size_t)b * S_ + qrow_w + lm) * (H_ * HD_) + h * HD_;
  bf16x8 qf[2];
  qf[0] = *(const bf16x8*)&Q[qg + quad * 8];
  qf[1] = *(const bf16x8*)&Q[qg + 32 + quad * 8];

  floatx4 o_acc[4] = {};
  float m_r[4], l_r[4];
#pragma unroll
  for (int r = 0; r < 4; ++r) { m_r[r] = -__builtin_inff(); l_r[r] = 0.f; }

  const int tr = tid >> 2;          // staging row 0..63
  const int tc = (tid & 3) * 8;     // staging col within 32-half

  for (int t = 0; t <= qt; ++t) {
    const int t0 = t * 64;
#pragma unroll
    for (int c = 0; c < 2; ++c) {
      async16(&K[((size_t)b * S_ + t0 + tr) * (HKV_ * HD_) + kvh * HD_ + c * 32 + tc],
              &Ks[c * 2048 + tid * 8]);
      async16(&VT[((size_t)kvh * HD_ + tr) * (size_t)(B_ * S_) + (size_t)b * S_ + t0 + c * 32 + tc],
              &Vs[c * 2048 + tid * 8]);
    }
    asm volatile("s_waitcnt vmcnt(0)" ::: "memory");
    __syncthreads();

    // S = Q K^T  (m=q, n=kv, k=hd)
    floatx4 s[4] = {};
#pragma unroll
    for (int ni = 0; ni < 4; ++ni)
#pragma unroll
      for (int kf = 0; kf < 2; ++kf) {
        bf16x8 kb = *(const bf16x8*)&Ks[kf * 2048 + (ni * 16 + lm) * 32 + quad * 8];
        s[ni] = __builtin_amdgcn_mfma_f32_16x16x32_bf16(qf[kf], kb, s[ni], 0, 0, 0);
      }

    const bool diag = (t == qt);
#pragma unroll
    for (int r = 0; r < 4; ++r) {
      const int qabs = qrow_w + quad * 4 + r;
      float sv[4];
      float rowmax = -__builtin_inff();
#pragma unroll
      for (int ni = 0; ni < 4; ++ni) {
        float v = s[ni][r] * 0.125f;
        if (diag && (t0 + ni * 16 + lm > qabs)) v = -__builtin_inff();
        sv[ni] = v;
        rowmax = fmaxf(rowmax, v);
      }
#pragma unroll
      for (int msk = 1; msk < 16; msk <<= 1)
        rowmax = fmaxf(rowmax, __shfl_xor(rowmax, msk, 64));
      const float mnew  = fmaxf(m_r[r], rowmax);
      const float alpha = __expf(m_r[r] - mnew);
      float psum = 0.f;
#pragma unroll
      for (int ni = 0; ni < 4; ++ni) {
        float p = __expf(sv[ni] - mnew);
        psum += p;
        const int col = ni * 16 + lm;  // kv within tile
        Ps[wid][(col >> 5) * 512 + (quad * 4 + r) * 32 + (col & 31)] = __float2bfloat16(p);
      }
#pragma unroll
      for (int msk = 1; msk < 16; msk <<= 1)
        psum += __shfl_xor(psum, msk, 64);
      l_r[r] = l_r[r] * alpha + psum;
      m_r[r] = mnew;
#pragma unroll
      for (int ni = 0; ni < 4; ++ni) o_acc[ni][r] *= alpha;
    }
    asm volatile("s_waitcnt lgkmcnt(0)" ::: "memory");  // Ps writes -> reads, same wave

    // O += P V   (A = P: m=q,k=kv ; B = V^T: n=hd,k=kv)
    bf16x8 pf[2];
#pragma unroll
    for (int kf = 0; kf < 2; ++kf)
      pf[kf] = *(const bf16x8*)&Ps[wid][kf * 512 + lm * 32 + quad * 8];
#pragma unroll
    for (int ni = 0; ni < 4; ++ni)
#pragma unroll
      for (int kf = 0; kf < 2; ++kf) {
        bf16x8 vb = *(const bf16x8*)&Vs[kf * 2048 + (ni * 16 + lm) * 32 + quad * 8];
        o_acc[ni] = __builtin_amdgcn_mfma_f32_16x16x32_bf16(pf[kf], vb, o_acc[ni], 0, 0, 0);
      }
    __syncthreads();
  }

#pragma unroll
  for (int ni = 0; ni < 4; ++ni)
#pragma unroll
    for (int r = 0; r < 4; ++r) {
      const size_t row = (size_t)b * S_ + qrow_w + quad * 4 + r;
      O[row * (H_ * HD_) + h * HD_ + ni * 16 + lm] =
          __float2bfloat16(o_acc[ni][r] / l_r[r]);
    }
}

// ---------------------------------------------------------------------------
extern "C" void kernel_launch(void* const* d_in, const int* in_sizes, int n_in,
                              void* d_out, int out_size, void* d_ws, size_t ws_size,
                              hipStream_t stream) {
  (void)in_sizes; (void)n_in; (void)out_size; (void)ws_size;
  const float* x  = (const float*)d_in[0];
  const float* wq = (const float*)d_in[1];
  const float* bq = (const float*)d_in[2];
  const float* wk = (const float*)d_in[3];
  const float* bk = (const float*)d_in[4];
  const float* wv = (const float*)d_in[5];
  const float* bv = (const float*)d_in[6];
  const float* wo = (const float*)d_in[7];
  const float* bo = (const float*)d_in[8];
  float* out = (float*)d_out;

  const int M = B_ * S_;        // 4096
  const int E = H_ * HD_;       // 2048
  const int EKV = HKV_ * HD_;   // 512

  char* ws = (char*)d_ws;
  size_t off = 0;
  auto alloc = [&](size_t bytes) {
    char* p = ws + off;
    off += (bytes + 255) & ~(size_t)255;
    return p;
  };
  bf16* xb  = (bf16*)alloc((size_t)M * D_ * 2);
  bf16* wqb = (bf16*)alloc((size_t)E * D_ * 2);
  bf16* wkb = (bf16*)alloc((size_t)EKV * D_ * 2);
  bf16* wvb = (bf16*)alloc((size_t)EKV * D_ * 2);
  bf16* wob = (bf16*)alloc((size_t)D_ * E * 2);
  bf16* Qb  = (bf16*)alloc((size_t)M * E * 2);
  bf16* Kb  = (bf16*)alloc((size_t)M * EKV * 2);
  bf16* VTb = (bf16*)alloc((size_t)EKV * M * 2);   // transposed V
  bf16* Ob  = (bf16*)alloc((size_t)M * E * 2);

  auto cvt = [&](const float* src, bf16* dst, size_t n) {
    int n8 = (int)(n / 8);
    f2b8<<<(n8 + 255) / 256, 256, 0, stream>>>(src, dst, n8);
  };
  cvt(x,  xb,  (size_t)M * D_);
  cvt(wq, wqb, (size_t)E * D_);
  cvt(wk, wkb, (size_t)EKV * D_);
  cvt(wv, wvb, (size_t)EKV * D_);
  cvt(wo, wob, (size_t)D_ * E);

  gemm_bt<bf16, false><<<dim3(E / 128,  M / 128), 256, 0, stream>>>(xb, wqb, bq, Qb,  M, E,   D_);
  gemm_bt<bf16, false><<<dim3(EKV / 128, M / 128), 256, 0, stream>>>(xb, wkb, bk, Kb,  M, EKV, D_);
  gemm_bt<bf16, true ><<<dim3(EKV / 128, M / 128), 256, 0, stream>>>(xb, wvb, bv, VTb, M, EKV, D_);

  attn_kernel<<<dim3(S_ / 64, H_, B_), 256, 0, stream>>>(Qb, Kb, VTb, Ob);

  gemm_bt<float, false><<<dim3(D_ / 128, M / 128), 256, 0, stream>>>(Ob, wob, bo, out, M, D_, D_);
}

// Round 2
// 383.060 us; speedup vs baseline: 1.3763x; 1.3763x over previous
//
#include <hip/hip_runtime.h>
#include <hip/hip_bf16.h>
#include <cmath>

#define B_   2
#define S_   2048
#define D_   2048
#define H_   32
#define HKV_ 8
#define HD_  64
// G = H/HKV = 4

using bf16 = __hip_bfloat16;
typedef __bf16 bf16x8 __attribute__((ext_vector_type(8)));
typedef float  floatx4 __attribute__((ext_vector_type(4)));

__device__ inline void async16(const void* g, void* l) {
  __builtin_amdgcn_global_load_lds(
      (const __attribute__((address_space(1))) void*)g,
      (__attribute__((address_space(3))) void*)l, 16, 0, 0);
}

__device__ inline void store_val(bf16* p, float v)  { *p = __float2bfloat16(v); }
__device__ inline void store_val(float* p, float v) { *p = v; }

#define MFMA16(a, b, c) __builtin_amdgcn_mfma_f32_16x16x32_bf16((a), (b), (c), 0, 0, 0)

// -------------------- fp32 -> bf16 conversion, 8 elems/thread --------------
__global__ void f2b8(const float* __restrict__ in, bf16* __restrict__ out, int n8) {
  int i = blockIdx.x * blockDim.x + threadIdx.x;
  if (i >= n8) return;
  float4 a  = ((const float4*)in)[2 * i];
  float4 b2 = ((const float4*)in)[2 * i + 1];
  alignas(16) bf16 t[8];
  t[0] = __float2bfloat16(a.x);  t[1] = __float2bfloat16(a.y);
  t[2] = __float2bfloat16(a.z);  t[3] = __float2bfloat16(a.w);
  t[4] = __float2bfloat16(b2.x); t[5] = __float2bfloat16(b2.y);
  t[6] = __float2bfloat16(b2.z); t[7] = __float2bfloat16(b2.w);
  ((uint4*)out)[i] = *(const uint4*)t;
}

// -------------------- shared GEMM tile body: C = A * B^T + bias ------------
// A tile rows bm*128..; B columns colb..colb+127 (rows of Bg); 256 threads.
template <typename OutT>
__device__ inline void gemm_body(const bf16* __restrict__ Ag, const bf16* __restrict__ Bg,
                                 const float* __restrict__ bias, OutT* __restrict__ C,
                                 int M, int Ncol, int K, int bm, int colb, bool tr,
                                 bf16* As, bf16* Bs) {
  const int tid  = threadIdx.x;
  const int wid  = tid >> 6, lane = tid & 63;
  const int lm   = lane & 15, quad = lane >> 4;
  const int wm   = (wid >> 1) * 64, wn = (wid & 1) * 64;

  floatx4 acc[4][4] = {};

  const int l0 = tid * 8;
  const int r0 = l0 >> 5, c0 = l0 & 31;
  const int r1 = r0 + 64;

  for (int k0 = 0; k0 < K; k0 += 32) {
    async16(Ag + (size_t)r0 * K + k0 + c0, &As[l0]);
    async16(Ag + (size_t)r1 * K + k0 + c0, &As[l0 + 2048]);
    async16(Bg + (size_t)r0 * K + k0 + c0, &Bs[l0]);
    async16(Bg + (size_t)r1 * K + k0 + c0, &Bs[l0 + 2048]);
    asm volatile("s_waitcnt vmcnt(0)" ::: "memory");
    __syncthreads();

    bf16x8 aF[4], bF[4];
#pragma unroll
    for (int mi = 0; mi < 4; ++mi)
      aF[mi] = *(const bf16x8*)&As[(wm + mi * 16 + lm) * 32 + quad * 8];
#pragma unroll
    for (int ni = 0; ni < 4; ++ni)
      bF[ni] = *(const bf16x8*)&Bs[(wn + ni * 16 + lm) * 32 + quad * 8];
#pragma unroll
    for (int mi = 0; mi < 4; ++mi)
#pragma unroll
      for (int ni = 0; ni < 4; ++ni)
        acc[mi][ni] = MFMA16(aF[mi], bF[ni], acc[mi][ni]);
    __syncthreads();
  }

#pragma unroll
  for (int ni = 0; ni < 4; ++ni) {
    const int col = colb + wn + ni * 16 + lm;
    const float bv = bias[col];
#pragma unroll
    for (int mi = 0; mi < 4; ++mi) {
      const int row0 = bm * 128 + wm + mi * 16 + quad * 4;
#pragma unroll
      for (int r = 0; r < 4; ++r) {
        float v = acc[mi][ni][r] + bv;
        if (tr)
          store_val(&C[(size_t)col * M + row0 + r], v);
        else
          store_val(&C[(size_t)(row0 + r) * Ncol + col], v);
      }
    }
  }
}

// Fused QKV projection: grid.x 0..23 -> Q(16) | K(4) | V^T(4) column tiles
__global__ __launch_bounds__(256, 2)
void gemm_qkv(const bf16* __restrict__ xb,
              const bf16* __restrict__ wq, const bf16* __restrict__ wk,
              const bf16* __restrict__ wv,
              const float* __restrict__ bq, const float* __restrict__ bk,
              const float* __restrict__ bv,
              bf16* __restrict__ Qo, bf16* __restrict__ Ko, bf16* __restrict__ Vo) {
  __shared__ bf16 As[128 * 32];
  __shared__ bf16 Bs[128 * 32];
  const int bn = blockIdx.x, bm = blockIdx.y;
  const int M = B_ * S_, K = D_;
  const bf16* Bm; const float* bias; bf16* C; int Ncol, colb; bool tr;
  if (bn < 16)      { Bm = wq; bias = bq; C = Qo; Ncol = H_ * HD_;   colb = bn * 128;        tr = false; }
  else if (bn < 20) { Bm = wk; bias = bk; C = Ko; Ncol = HKV_ * HD_; colb = (bn - 16) * 128; tr = false; }
  else              { Bm = wv; bias = bv; C = Vo; Ncol = HKV_ * HD_; colb = (bn - 20) * 128; tr = true;  }
  gemm_body<bf16>(xb + (size_t)bm * 128 * K, Bm + (size_t)colb * K, bias, C,
                  M, Ncol, K, bm, colb, tr, As, Bs);
}

// Plain GEMM (O-projection): C fp32 = A * B^T + bias
__global__ __launch_bounds__(256, 2)
void gemm_o(const bf16* __restrict__ A, const bf16* __restrict__ Bm,
            const float* __restrict__ bias, float* __restrict__ C,
            int M, int Ncol, int K) {
  __shared__ bf16 As[128 * 32];
  __shared__ bf16 Bs[128 * 32];
  const int bn = blockIdx.x, bm = blockIdx.y;
  gemm_body<float>(A + (size_t)bm * 128 * K, Bm + (size_t)bn * 128 * K, bias, C,
                   M, Ncol, K, bm, bn * 128, false, As, Bs);
}

// -------------------- causal GQA flash attention, v2 ------------------------
// Block = 4 waves = 2 heads x 2 complementary q-tiles (pair, 31-pair) of one
// (b, kvh). Each wave: 64 q-rows. Unnormalized softmax (no max tracking);
// row-sum l via MFMA against an all-ones B fragment.
__global__ __launch_bounds__(256, 2)
void attn_kernel(const bf16* __restrict__ Q, const bf16* __restrict__ K,
                 const bf16* __restrict__ VT, bf16* __restrict__ O) {
  const int pair = blockIdx.x;          // 0..15
  const int kvh  = blockIdx.y >> 1;     // 0..7
  const int hp   = blockIdx.y & 1;      // head-pair within group
  const int b    = blockIdx.z;
  const int tid  = threadIdx.x;
  const int wid  = tid >> 6, lane = tid & 63;
  const int lm = lane & 15, quad = lane >> 4;

  const int hi_t  = 31 - pair;
  const int myq   = (wid < 2) ? hi_t : pair;   // this wave's q-tile
  const int mylim = myq + 1;                   // KV tiles this wave needs
  const int nt    = hi_t + 1;                  // block iterations
  const int head  = kvh * 4 + hp * 2 + (wid & 1);

  __shared__ bf16 Ks[2 * 64 * 32];     // [kv-half? no: hd-half][kv][32hd]
  __shared__ bf16 Vs[2 * 64 * 32];     // [kv-half][hd][32kv]
  __shared__ bf16 Ps[4 * 64 * 68];     // per-wave P, row stride 68 (bank-clean)
  bf16* Pw = &Ps[wid * (64 * 68)];

  const int q0 = myq * 64;

  bf16x8 qf[4][2];
#pragma unroll
  for (int mi = 0; mi < 4; ++mi) {
    const size_t qg = ((size_t)(b * S_ + q0 + mi * 16 + lm)) * (H_ * HD_) + head * HD_;
#pragma unroll
    for (int kf = 0; kf < 2; ++kf)
      qf[mi][kf] = *(const bf16x8*)&Q[qg + kf * 32 + quad * 8];
  }

  bf16x8 onesv;
#pragma unroll
  for (int j = 0; j < 8; ++j) onesv[j] = (__bf16)1.0f;

  floatx4 o_acc[4][4] = {};
  floatx4 lacc[4] = {};

  const int tr = tid >> 2;            // staging row 0..63
  const int tc = (tid & 3) * 8;       // staging col within 32-half
  const float sc = 0.125f * 1.4426950408889634f;   // scale * log2(e)

  for (int t = 0; t < nt; ++t) {
    const int t0 = t * 64;
#pragma unroll
    for (int c = 0; c < 2; ++c) {
      async16(&K[(size_t)(b * S_ + t0 + tr) * (HKV_ * HD_) + kvh * HD_ + c * 32 + tc],
              &Ks[c * 2048 + tid * 8]);
      async16(&VT[(size_t)(kvh * HD_ + tr) * (B_ * S_) + b * S_ + t0 + c * 32 + tc],
              &Vs[c * 2048 + tid * 8]);
    }
    asm volatile("s_waitcnt vmcnt(0)" ::: "memory");
    __syncthreads();

    if (t < mylim) {
      bf16x8 kb[4][2];
#pragma unroll
      for (int ni = 0; ni < 4; ++ni)
#pragma unroll
        for (int kf = 0; kf < 2; ++kf)
          kb[ni][kf] = *(const bf16x8*)&Ks[kf * 2048 + (ni * 16 + lm) * 32 + quad * 8];

      const bool diag = (t == mylim - 1);
#pragma unroll
      for (int mi = 0; mi < 4; ++mi) {
        floatx4 s[4] = {};
#pragma unroll
        for (int ni = 0; ni < 4; ++ni)
#pragma unroll
          for (int kf = 0; kf < 2; ++kf)
            s[ni] = MFMA16(qf[mi][kf], kb[ni][kf], s[ni]);
#pragma unroll
        for (int r = 0; r < 4; ++r) {
          const int row  = mi * 16 + quad * 4 + r;
          const int qabs = q0 + row;
#pragma unroll
          for (int ni = 0; ni < 4; ++ni) {
            float v = fminf(s[ni][r] * sc, 30.f);
            float p = exp2f(v);
            if (diag && (t0 + ni * 16 + lm > qabs)) p = 0.f;
            Pw[row * 68 + ni * 16 + lm] = __float2bfloat16(p);
          }
        }
      }
      asm volatile("s_waitcnt lgkmcnt(0)" ::: "memory");  // Ps writes -> reads, same wave

      bf16x8 pf[4][2];
#pragma unroll
      for (int mi = 0; mi < 4; ++mi)
#pragma unroll
        for (int kf = 0; kf < 2; ++kf)
          pf[mi][kf] = *(const bf16x8*)&Pw[(mi * 16 + lm) * 68 + kf * 32 + quad * 8];

#pragma unroll
      for (int mi = 0; mi < 4; ++mi)
#pragma unroll
        for (int kf = 0; kf < 2; ++kf)
          lacc[mi] = MFMA16(pf[mi][kf], onesv, lacc[mi]);

#pragma unroll
      for (int ni = 0; ni < 4; ++ni)
#pragma unroll
        for (int kf = 0; kf < 2; ++kf) {
          bf16x8 vb = *(const bf16x8*)&Vs[kf * 2048 + (ni * 16 + lm) * 32 + quad * 8];
#pragma unroll
          for (int mi = 0; mi < 4; ++mi)
            o_acc[mi][ni] = MFMA16(pf[mi][kf], vb, o_acc[mi][ni]);
        }
    }
    __syncthreads();
  }

#pragma unroll
  for (int mi = 0; mi < 4; ++mi) {
    floatx4 rl;
#pragma unroll
    for (int r = 0; r < 4; ++r) rl[r] = 1.f / lacc[mi][r];
#pragma unroll
    for (int ni = 0; ni < 4; ++ni)
#pragma unroll
      for (int r = 0; r < 4; ++r) {
        const size_t rowg = (size_t)(b * S_ + q0 + mi * 16 + quad * 4 + r);
        O[rowg * (H_ * HD_) + head * HD_ + ni * 16 + lm] =
            __float2bfloat16(o_acc[mi][ni][r] * rl[r]);
      }
  }
}

// ---------------------------------------------------------------------------
extern "C" void kernel_launch(void* const* d_in, const int* in_sizes, int n_in,
                              void* d_out, int out_size, void* d_ws, size_t ws_size,
                              hipStream_t stream) {
  (void)in_sizes; (void)n_in; (void)out_size; (void)ws_size;
  const float* x  = (const float*)d_in[0];
  const float* wq = (const float*)d_in[1];
  const float* bq = (const float*)d_in[2];
  const float* wk = (const float*)d_in[3];
  const float* bk = (const float*)d_in[4];
  const float* wv = (const float*)d_in[5];
  const float* bv = (const float*)d_in[6];
  const float* wo = (const float*)d_in[7];
  const float* bo = (const float*)d_in[8];
  float* out = (float*)d_out;

  const int M = B_ * S_;        // 4096
  const int E = H_ * HD_;       // 2048
  const int EKV = HKV_ * HD_;   // 512

  char* ws = (char*)d_ws;
  size_t off = 0;
  auto alloc = [&](size_t bytes) {
    char* p = ws + off;
    off += (bytes + 255) & ~(size_t)255;
    return p;
  };
  bf16* xb  = (bf16*)alloc((size_t)M * D_ * 2);
  bf16* wqb = (bf16*)alloc((size_t)E * D_ * 2);
  bf16* wkb = (bf16*)alloc((size_t)EKV * D_ * 2);
  bf16* wvb = (bf16*)alloc((size_t)EKV * D_ * 2);
  bf16* wob = (bf16*)alloc((size_t)D_ * E * 2);
  bf16* Qb  = (bf16*)alloc((size_t)M * E * 2);
  bf16* Kb  = (bf16*)alloc((size_t)M * EKV * 2);
  bf16* VTb = (bf16*)alloc((size_t)EKV * M * 2);   // transposed V
  bf16* Ob  = (bf16*)alloc((size_t)M * E * 2);

  auto cvt = [&](const float* src, bf16* dst, size_t n) {
    int n8 = (int)(n / 8);
    f2b8<<<(n8 + 255) / 256, 256, 0, stream>>>(src, dst, n8);
  };
  cvt(x,  xb,  (size_t)M * D_);
  cvt(wq, wqb, (size_t)E * D_);
  cvt(wk, wkb, (size_t)EKV * D_);
  cvt(wv, wvb, (size_t)EKV * D_);
  cvt(wo, wob, (size_t)D_ * E);

  gemm_qkv<<<dim3(24, M / 128), 256, 0, stream>>>(xb, wqb, wkb, wvb, bq, bk, bv,
                                                  Qb, Kb, VTb);

  attn_kernel<<<dim3(16, 16, 2), 256, 0, stream>>>(Qb, Kb, VTb, Ob);

  gemm_o<<<dim3(D_ / 128, M / 128), 256, 0, stream>>>(Ob, wob, bo, out, M, D_, D_);
}

// Round 4
// 370.461 us; speedup vs baseline: 1.4231x; 1.0340x over previous
//
#include <hip/hip_runtime.h>
#include <hip/hip_bf16.h>
#include <cmath>

#define B_   2
#define S_   2048
#define D_   2048
#define H_   32
#define HKV_ 8
#define HD_  64
// G = H/HKV = 4

using bf16 = __hip_bfloat16;
typedef __bf16    bf16x8 __attribute__((ext_vector_type(8)));
typedef float     floatx4 __attribute__((ext_vector_type(4)));
typedef _Float16  half4 __attribute__((ext_vector_type(4)));

__device__ inline void async16(const void* g, void* l) {
  __builtin_amdgcn_global_load_lds(
      (const __attribute__((address_space(1))) void*)g,
      (__attribute__((address_space(3))) void*)l, 16, 0, 0);
}

__device__ inline void store_val(bf16* p, float v)     { *p = __float2bfloat16(v); }
__device__ inline void store_val(float* p, float v)    { *p = v; }
__device__ inline void store_val(_Float16* p, float v) { *p = (_Float16)v; }

#define MFMA32B(a, b, c) __builtin_amdgcn_mfma_f32_16x16x32_bf16((a), (b), (c), 0, 0, 0)
#define MFMA16H(a, b, c) __builtin_amdgcn_mfma_f32_16x16x16f16((a), (b), (c), 0, 0, 0)

// -------------------- fp32 -> bf16 conversion, 8 elems/thread --------------
__global__ void f2b8(const float* __restrict__ in, bf16* __restrict__ out, int n8) {
  int i = blockIdx.x * blockDim.x + threadIdx.x;
  if (i >= n8) return;
  float4 a  = ((const float4*)in)[2 * i];
  float4 b2 = ((const float4*)in)[2 * i + 1];
  alignas(16) bf16 t[8];
  t[0] = __float2bfloat16(a.x);  t[1] = __float2bfloat16(a.y);
  t[2] = __float2bfloat16(a.z);  t[3] = __float2bfloat16(a.w);
  t[4] = __float2bfloat16(b2.x); t[5] = __float2bfloat16(b2.y);
  t[6] = __float2bfloat16(b2.z); t[7] = __float2bfloat16(b2.w);
  ((uint4*)out)[i] = *(const uint4*)t;
}

// -------------------- shared GEMM tile body: C = A * B^T + bias ------------
template <typename OutT>
__device__ inline void gemm_body(const bf16* __restrict__ Ag, const bf16* __restrict__ Bg,
                                 const float* __restrict__ bias, OutT* __restrict__ C,
                                 int M, int Ncol, int K, int bm, int colb, bool tr,
                                 bf16* As, bf16* Bs) {
  const int tid  = threadIdx.x;
  const int wid  = tid >> 6, lane = tid & 63;
  const int lm   = lane & 15, quad = lane >> 4;
  const int wm   = (wid >> 1) * 64, wn = (wid & 1) * 64;

  floatx4 acc[4][4] = {};

  const int l0 = tid * 8;
  const int r0 = l0 >> 5, c0 = l0 & 31;
  const int r1 = r0 + 64;

  for (int k0 = 0; k0 < K; k0 += 32) {
    async16(Ag + (size_t)r0 * K + k0 + c0, &As[l0]);
    async16(Ag + (size_t)r1 * K + k0 + c0, &As[l0 + 2048]);
    async16(Bg + (size_t)r0 * K + k0 + c0, &Bs[l0]);
    async16(Bg + (size_t)r1 * K + k0 + c0, &Bs[l0 + 2048]);
    asm volatile("s_waitcnt vmcnt(0)" ::: "memory");
    __syncthreads();

    bf16x8 aF[4], bF[4];
#pragma unroll
    for (int mi = 0; mi < 4; ++mi)
      aF[mi] = *(const bf16x8*)&As[(wm + mi * 16 + lm) * 32 + quad * 8];
#pragma unroll
    for (int ni = 0; ni < 4; ++ni)
      bF[ni] = *(const bf16x8*)&Bs[(wn + ni * 16 + lm) * 32 + quad * 8];
#pragma unroll
    for (int mi = 0; mi < 4; ++mi)
#pragma unroll
      for (int ni = 0; ni < 4; ++ni)
        acc[mi][ni] = MFMA32B(aF[mi], bF[ni], acc[mi][ni]);
    __syncthreads();
  }

#pragma unroll
  for (int ni = 0; ni < 4; ++ni) {
    const int col = colb + wn + ni * 16 + lm;
    const float bv = bias[col];
#pragma unroll
    for (int mi = 0; mi < 4; ++mi) {
      const int row0 = bm * 128 + wm + mi * 16 + quad * 4;
#pragma unroll
      for (int r = 0; r < 4; ++r) {
        float v = acc[mi][ni][r] + bv;
        if (tr)
          store_val(&C[(size_t)col * M + row0 + r], v);
        else
          store_val(&C[(size_t)(row0 + r) * Ncol + col], v);
      }
    }
  }
}

// Fused QKV projection: grid.x 0..23 -> Q(16) | K(4) | V^T(4, fp16) tiles
__global__ __launch_bounds__(256, 2)
void gemm_qkv(const bf16* __restrict__ xb,
              const bf16* __restrict__ wq, const bf16* __restrict__ wk,
              const bf16* __restrict__ wv,
              const float* __restrict__ bq, const float* __restrict__ bk,
              const float* __restrict__ bv,
              bf16* __restrict__ Qo, bf16* __restrict__ Ko, _Float16* __restrict__ Vo) {
  __shared__ bf16 As[128 * 32];
  __shared__ bf16 Bs[128 * 32];
  const int bn = blockIdx.x, bm = blockIdx.y;
  const int M = B_ * S_, K = D_;
  if (bn < 16) {
    gemm_body<bf16>(xb + (size_t)bm * 128 * K, wq + (size_t)(bn * 128) * K, bq, Qo,
                    M, H_ * HD_, K, bm, bn * 128, false, As, Bs);
  } else if (bn < 20) {
    gemm_body<bf16>(xb + (size_t)bm * 128 * K, wk + (size_t)((bn - 16) * 128) * K, bk, Ko,
                    M, HKV_ * HD_, K, bm, (bn - 16) * 128, false, As, Bs);
  } else {
    gemm_body<_Float16>(xb + (size_t)bm * 128 * K, wv + (size_t)((bn - 20) * 128) * K, bv, Vo,
                        M, HKV_ * HD_, K, bm, (bn - 20) * 128, true, As, Bs);
  }
}

// Plain GEMM (O-projection): C fp32 = A * B^T + bias
__global__ __launch_bounds__(256, 2)
void gemm_o(const bf16* __restrict__ A, const bf16* __restrict__ Bm,
            const float* __restrict__ bias, float* __restrict__ C,
            int M, int Ncol, int K) {
  __shared__ bf16 As[128 * 32];
  __shared__ bf16 Bs[128 * 32];
  const int bn = blockIdx.x, bm = blockIdx.y;
  gemm_body<float>(A + (size_t)bm * 128 * K, Bm + (size_t)bn * 128 * K, bias, C,
                   M, Ncol, K, bm, bn * 128, false, As, Bs);
}

// -------------------- causal GQA flash attention, v3 ------------------------
// Register-resident P: S^T = K*Q^T via operand-swapped 16x16x32 bf16 MFMA;
// P (exp) packs directly into B-frags of 16x16x16 f16 MFMA (PV and row-sum l).
// Block = 4 waves = 2 heads x {q-tile i, q-tile 63-i} (32 q-rows each),
// sharing double-buffered K (bf16) / V^T (f16) LDS tiles of 64 kv.
__global__ __launch_bounds__(256, 3)
void attn_kernel(const bf16* __restrict__ Q, const bf16* __restrict__ K,
                 const _Float16* __restrict__ VT, bf16* __restrict__ O) {
  const int pair = blockIdx.x;          // 0..31 (32-row q-tile pairs)
  const int kvh  = blockIdx.y >> 1;     // 0..7
  const int hp   = blockIdx.y & 1;
  const int b    = blockIdx.z;
  const int tid  = threadIdx.x;
  const int wid  = tid >> 6, lane = tid & 63;
  const int lm = lane & 15, quad = lane >> 4;

  const int myq32 = (wid < 2) ? (63 - pair) : pair;   // this wave's 32-row q-tile
  const int mylim = myq32 / 2 + 1;                    // 64-kv tiles this wave needs
  const int nt    = (63 - pair) / 2 + 1;              // block iterations
  const int head  = kvh * 4 + hp * 2 + (wid & 1);
  const int q0    = myq32 * 32;

  __shared__ bf16     Ks[2 * 64 * 64];   // dbuf, [buf][hd-half][kv][32]
  __shared__ _Float16 Vs[2 * 64 * 64];   // dbuf, [buf][kv-half][hd][32kv]

  // Q fragments (B-layout: lane holds Q[q=lm][hd=quad*8+j])
  bf16x8 qf[2][2];
#pragma unroll
  for (int qn = 0; qn < 2; ++qn) {
    const size_t qg = ((size_t)(b * S_ + q0 + qn * 16 + lm)) * (H_ * HD_) + head * HD_;
#pragma unroll
    for (int kf = 0; kf < 2; ++kf)
      qf[qn][kf] = *(const bf16x8*)&Q[qg + kf * 32 + quad * 8];
  }

  half4 onesh;
#pragma unroll
  for (int j = 0; j < 4; ++j) onesh[j] = (_Float16)1.0f;

  floatx4 o_acc[2][4] = {};   // [qn][hd-chunk] : O^T[hd=nh*16+quad*4+r][q=lm]
  floatx4 lacc[2] = {};

  const int tr = tid >> 2;          // staging row 0..63
  const int tc = (tid & 3) * 8;     // staging col within 32-half
  const float sc = 0.125f * 1.4426950408889634f;

  auto stage = [&](int t, int buf) {
    const int t0 = t * 64;
#pragma unroll
    for (int c = 0; c < 2; ++c) {
      async16(&K[(size_t)(b * S_ + t0 + tr) * (HKV_ * HD_) + kvh * HD_ + c * 32 + tc],
              &Ks[buf * 4096 + c * 2048 + tid * 8]);
      async16(&VT[(size_t)(kvh * HD_ + tr) * (B_ * S_) + b * S_ + t0 + c * 32 + tc],
              &Vs[buf * 4096 + c * 2048 + tid * 8]);
    }
  };

  stage(0, 0);

  for (int t = 0; t < nt; ++t) {
    const int cur = t & 1;
    asm volatile("s_waitcnt vmcnt(0)" ::: "memory");
    __syncthreads();
    if (t + 1 < nt) stage(t + 1, cur ^ 1);   // prefetch overlaps compute below

    if (t < mylim) {
      const bf16*     Kb = &Ks[cur * 4096];
      const _Float16* Vb = &Vs[cur * 4096];
      const int t0 = t * 64;
      const bool diag = (t == mylim - 1);

      bf16x8 kb[4][2];
#pragma unroll
      for (int kc = 0; kc < 4; ++kc)
#pragma unroll
        for (int kf = 0; kf < 2; ++kf)
          kb[kc][kf] = *(const bf16x8*)&Kb[kf * 2048 + (kc * 16 + lm) * 32 + quad * 8];

      half4 pb[2][4];
#pragma unroll
      for (int qn = 0; qn < 2; ++qn) {
        floatx4 sT[4] = {};
#pragma unroll
        for (int kc = 0; kc < 4; ++kc)
#pragma unroll
          for (int kf = 0; kf < 2; ++kf)
            sT[kc] = MFMA32B(kb[kc][kf], qf[qn][kf], sT[kc]);  // S^T[kv][q]

        const int qabs = q0 + qn * 16 + lm;
#pragma unroll
        for (int kc = 0; kc < 4; ++kc) {
          float p[4];
#pragma unroll
          for (int r = 0; r < 4; ++r)
            p[r] = exp2f(fminf(sT[kc][r] * sc, 15.f));
          if (diag) {
            const int kvb = t0 + kc * 16 + quad * 4;
#pragma unroll
            for (int r = 0; r < 4; ++r)
              if (kvb + r > qabs) p[r] = 0.f;
          }
          half4 pk;
#pragma unroll
          for (int r = 0; r < 4; ++r) pk[r] = (_Float16)p[r];
          pb[qn][kc] = pk;
        }
      }

      // row sums via MFMA (ones as A): lacc[qn] regs all hold l[q=lm]
#pragma unroll
      for (int qn = 0; qn < 2; ++qn)
#pragma unroll
        for (int kc = 0; kc < 4; ++kc)
          lacc[qn] = MFMA16H(onesh, pb[qn][kc], lacc[qn]);

      // O^T += V^T * P^T
#pragma unroll
      for (int kc = 0; kc < 4; ++kc)
#pragma unroll
        for (int nh = 0; nh < 4; ++nh) {
          half4 va = *(const half4*)&Vb[(kc >> 1) * 2048 + (nh * 16 + lm) * 32 +
                                        (kc & 1) * 16 + quad * 4];
#pragma unroll
          for (int qn = 0; qn < 2; ++qn)
            o_acc[qn][nh] = MFMA16H(va, pb[qn][kc], o_acc[qn][nh]);
        }
    }
  }

#pragma unroll
  for (int qn = 0; qn < 2; ++qn) {
    const float rl = 1.f / lacc[qn][0];
    const size_t rowg = (size_t)(b * S_ + q0 + qn * 16 + lm);
#pragma unroll
    for (int nh = 0; nh < 4; ++nh) {
      alignas(8) bf16 tmp[4];
#pragma unroll
      for (int r = 0; r < 4; ++r)
        tmp[r] = __float2bfloat16(o_acc[qn][nh][r] * rl);
      *(uint2*)&O[rowg * (H_ * HD_) + head * HD_ + nh * 16 + quad * 4] = *(uint2*)tmp;
    }
  }
}

// ---------------------------------------------------------------------------
extern "C" void kernel_launch(void* const* d_in, const int* in_sizes, int n_in,
                              void* d_out, int out_size, void* d_ws, size_t ws_size,
                              hipStream_t stream) {
  (void)in_sizes; (void)n_in; (void)out_size; (void)ws_size;
  const float* x  = (const float*)d_in[0];
  const float* wq = (const float*)d_in[1];
  const float* bq = (const float*)d_in[2];
  const float* wk = (const float*)d_in[3];
  const float* bk = (const float*)d_in[4];
  const float* wv = (const float*)d_in[5];
  const float* bv = (const float*)d_in[6];
  const float* wo = (const float*)d_in[7];
  const float* bo = (const float*)d_in[8];
  float* out = (float*)d_out;

  const int M = B_ * S_;        // 4096
  const int E = H_ * HD_;       // 2048
  const int EKV = HKV_ * HD_;   // 512

  char* ws = (char*)d_ws;
  size_t off = 0;
  auto alloc = [&](size_t bytes) {
    char* p = ws + off;
    off += (bytes + 255) & ~(size_t)255;
    return p;
  };
  bf16* xb  = (bf16*)alloc((size_t)M * D_ * 2);
  bf16* wqb = (bf16*)alloc((size_t)E * D_ * 2);
  bf16* wkb = (bf16*)alloc((size_t)EKV * D_ * 2);
  bf16* wvb = (bf16*)alloc((size_t)EKV * D_ * 2);
  bf16* wob = (bf16*)alloc((size_t)D_ * E * 2);
  bf16* Qb  = (bf16*)alloc((size_t)M * E * 2);
  bf16* Kb  = (bf16*)alloc((size_t)M * EKV * 2);
  _Float16* VTb = (_Float16*)alloc((size_t)EKV * M * 2);  // transposed V, fp16
  bf16* Ob  = (bf16*)alloc((size_t)M * E * 2);

  auto cvt = [&](const float* src, bf16* dst, size_t n) {
    int n8 = (int)(n / 8);
    f2b8<<<(n8 + 255) / 256, 256, 0, stream>>>(src, dst, n8);
  };
  cvt(x,  xb,  (size_t)M * D_);
  cvt(wq, wqb, (size_t)E * D_);
  cvt(wk, wkb, (size_t)EKV * D_);
  cvt(wv, wvb, (size_t)EKV * D_);
  cvt(wo, wob, (size_t)D_ * E);

  gemm_qkv<<<dim3(24, M / 128), 256, 0, stream>>>(xb, wqb, wkb, wvb, bq, bk, bv,
                                                  Qb, Kb, VTb);

  attn_kernel<<<dim3(32, 16, 2), 256, 0, stream>>>(Qb, Kb, VTb, Ob);

  gemm_o<<<dim3(D_ / 128, M / 128), 256, 0, stream>>>(Ob, wob, bo, out, M, D_, D_);
}

// Round 5
// 300.721 us; speedup vs baseline: 1.7532x; 1.2319x over previous
//
#include <hip/hip_runtime.h>
#include <hip/hip_bf16.h>
#include <cmath>

#define B_   2
#define S_   2048
#define D_   2048
#define H_   32
#define HKV_ 8
#define HD_  64
// G = H/HKV = 4

using bf16 = __hip_bfloat16;
typedef __bf16    bf16x8 __attribute__((ext_vector_type(8)));
typedef float     floatx4 __attribute__((ext_vector_type(4)));
typedef _Float16  half4 __attribute__((ext_vector_type(4)));

#if __has_builtin(__builtin_amdgcn_exp2f)
#define EXP2(x) __builtin_amdgcn_exp2f(x)
#else
#define EXP2(x) exp2f(x)
#endif

#define QSCALE 0.18033688011112042f   // 0.125 * log2(e)

__device__ inline void async16(const void* g, void* l) {
  __builtin_amdgcn_global_load_lds(
      (const __attribute__((address_space(1))) void*)g,
      (__attribute__((address_space(3))) void*)l, 16, 0, 0);
}

#define MFMA32B(a, b, c) __builtin_amdgcn_mfma_f32_16x16x32_bf16((a), (b), (c), 0, 0, 0)
#define MFMA16H(a, b, c) __builtin_amdgcn_mfma_f32_16x16x16f16((a), (b), (c), 0, 0, 0)

// ---------- fused fp32->bf16 conversion for all 5 tensors (wq pre-scaled) ---
// chunk sizes (8-elem units): x 1048576 | wq 524288 | wk 131072 | wv 131072 | wo 524288
__global__ void f2b_all(const float* __restrict__ x,  const float* __restrict__ wq,
                        const float* __restrict__ wk, const float* __restrict__ wv,
                        const float* __restrict__ wo,
                        bf16* __restrict__ xb,  bf16* __restrict__ wqb,
                        bf16* __restrict__ wkb, bf16* __restrict__ wvb,
                        bf16* __restrict__ wob) {
  const int i = blockIdx.x * blockDim.x + threadIdx.x;
  const float* src; bf16* dst; int off; float scale = 1.0f;
  if (i < 1048576)      { src = x;  dst = xb;  off = 0; }
  else if (i < 1572864) { src = wq; dst = wqb; off = 1048576; scale = QSCALE; }
  else if (i < 1703936) { src = wk; dst = wkb; off = 1572864; }
  else if (i < 1835008) { src = wv; dst = wvb; off = 1703936; }
  else                  { src = wo; dst = wob; off = 1835008; }
  const int j = i - off;
  float4 a  = ((const float4*)src)[2 * j];
  float4 b2 = ((const float4*)src)[2 * j + 1];
  alignas(16) bf16 t[8];
  t[0] = __float2bfloat16(a.x * scale);  t[1] = __float2bfloat16(a.y * scale);
  t[2] = __float2bfloat16(a.z * scale);  t[3] = __float2bfloat16(a.w * scale);
  t[4] = __float2bfloat16(b2.x * scale); t[5] = __float2bfloat16(b2.y * scale);
  t[6] = __float2bfloat16(b2.z * scale); t[7] = __float2bfloat16(b2.w * scale);
  ((uint4*)dst)[j] = *(const uint4*)t;
}

// -------------------- shared GEMM tile body: C = A * B^T + bias*bscale ------
// MODE 0: bf16 row-major; MODE 1: f32 row-major; MODE 2: f16 V-tiled layout
template <int MODE, typename OutT>
__device__ inline void gemm_body(const bf16* __restrict__ Ag, const bf16* __restrict__ Bg,
                                 const float* __restrict__ bias, float bscale,
                                 OutT* __restrict__ C, int Ncol, int K, int bm, int colb,
                                 bf16* As, bf16* Bs) {
  const int tid  = threadIdx.x;
  const int wid  = tid >> 6, lane = tid & 63;
  const int lm   = lane & 15, quad = lane >> 4;
  const int wm   = (wid >> 1) * 64, wn = (wid & 1) * 64;

  floatx4 acc[4][4] = {};

  const int l0 = tid * 8;
  const int r0 = l0 >> 5, c0 = l0 & 31;
  const int r1 = r0 + 64;

  for (int k0 = 0; k0 < K; k0 += 32) {
    async16(Ag + (size_t)r0 * K + k0 + c0, &As[l0]);
    async16(Ag + (size_t)r1 * K + k0 + c0, &As[l0 + 2048]);
    async16(Bg + (size_t)r0 * K + k0 + c0, &Bs[l0]);
    async16(Bg + (size_t)r1 * K + k0 + c0, &Bs[l0 + 2048]);
    asm volatile("s_waitcnt vmcnt(0)" ::: "memory");
    __syncthreads();

    bf16x8 aF[4], bF[4];
#pragma unroll
    for (int mi = 0; mi < 4; ++mi)
      aF[mi] = *(const bf16x8*)&As[(wm + mi * 16 + lm) * 32 + quad * 8];
#pragma unroll
    for (int ni = 0; ni < 4; ++ni)
      bF[ni] = *(const bf16x8*)&Bs[(wn + ni * 16 + lm) * 32 + quad * 8];
#pragma unroll
    for (int mi = 0; mi < 4; ++mi)
#pragma unroll
      for (int ni = 0; ni < 4; ++ni)
        acc[mi][ni] = MFMA32B(aF[mi], bF[ni], acc[mi][ni]);
    __syncthreads();
  }

#pragma unroll
  for (int ni = 0; ni < 4; ++ni) {
    const int col = colb + wn + ni * 16 + lm;
    const float bv = bias[col] * bscale;
#pragma unroll
    for (int mi = 0; mi < 4; ++mi) {
      const int row0 = bm * 128 + wm + mi * 16 + quad * 4;
#pragma unroll
      for (int r = 0; r < 4; ++r) {
        float v = acc[mi][ni][r] + bv;
        if constexpr (MODE == 0) {
          ((bf16*)C)[(size_t)(row0 + r) * Ncol + col] = __float2bfloat16(v);
        } else if constexpr (MODE == 1) {
          ((float*)C)[(size_t)(row0 + r) * Ncol + col] = v;
        } else {
          // V tiled: per (b,kvh), 32 tiles of 64kv x 64hd, inner order
          // [kc(4)][nh(4)][quad(4)][lm(16)][j(4)]
          const int rowg = row0 + r;
          const int b    = rowg >> 11, s = rowg & 2047;
          const int tile = s >> 6,  kvin = s & 63;
          const int kc = kvin >> 4, qd = (kvin >> 2) & 3, j = kvin & 3;
          const int kvh = col >> 6, hd = col & 63;
          const int nh = hd >> 4, lmw = hd & 15;
          const size_t addr = ((size_t)((b * 8 + kvh) * 32 + tile) << 12) |
                              (((kc * 4 + nh) * 4 + qd) << 6) | (lmw << 2) | j;
          ((_Float16*)C)[addr] = (_Float16)v;
        }
      }
    }
  }
}

// Fused QKV projection: grid.x 0..23 -> Q(16, pre-scaled) | K(4) | V(4, tiled f16)
__global__ __launch_bounds__(256, 2)
void gemm_qkv(const bf16* __restrict__ xb,
              const bf16* __restrict__ wq, const bf16* __restrict__ wk,
              const bf16* __restrict__ wv,
              const float* __restrict__ bq, const float* __restrict__ bk,
              const float* __restrict__ bv,
              bf16* __restrict__ Qo, bf16* __restrict__ Ko, _Float16* __restrict__ VG) {
  __shared__ bf16 As[128 * 32];
  __shared__ bf16 Bs[128 * 32];
  const int bn = blockIdx.x, bm = blockIdx.y;
  const int K = D_;
  if (bn < 16) {
    gemm_body<0, bf16>(xb + (size_t)bm * 128 * K, wq + (size_t)(bn * 128) * K, bq, QSCALE,
                       Qo, H_ * HD_, K, bm, bn * 128, As, Bs);
  } else if (bn < 20) {
    gemm_body<0, bf16>(xb + (size_t)bm * 128 * K, wk + (size_t)((bn - 16) * 128) * K, bk, 1.0f,
                       Ko, HKV_ * HD_, K, bm, (bn - 16) * 128, As, Bs);
  } else {
    gemm_body<2, _Float16>(xb + (size_t)bm * 128 * K, wv + (size_t)((bn - 20) * 128) * K, bv, 1.0f,
                           VG, HKV_ * HD_, K, bm, (bn - 20) * 128, As, Bs);
  }
}

// Plain GEMM (O-projection): C fp32 = A * B^T + bias
__global__ __launch_bounds__(256, 2)
void gemm_o(const bf16* __restrict__ A, const bf16* __restrict__ Bm,
            const float* __restrict__ bias, float* __restrict__ C,
            int Ncol, int K) {
  __shared__ bf16 As[128 * 32];
  __shared__ bf16 Bs[128 * 32];
  const int bn = blockIdx.x, bm = blockIdx.y;
  gemm_body<1, float>(A + (size_t)bm * 128 * K, Bm + (size_t)bn * 128 * K, bias, 1.0f,
                      C, Ncol, K, bm, bn * 128, As, Bs);
}

// -------------------- causal GQA flash attention, v4 ------------------------
// Block = (pair, b, kvh): 4 waves = 4 heads of one GQA group sharing K/V LDS.
// Each wave owns two 16-row q-tiles (hi=127-pair, lo=pair), processed in one
// interleaved kv-loop (lo active while t < nt_lo). P register-resident.
// Q pre-scaled by 0.125*log2e -> p = exp2(s) directly.
__global__ __launch_bounds__(256, 4)
void attn_kernel(const bf16* __restrict__ Q, const bf16* __restrict__ K,
                 const _Float16* __restrict__ VG, bf16* __restrict__ O) {
  const int tid = threadIdx.x;
  const int wid = tid >> 6, lane = tid & 63;
  const int lm = lane & 15, quad = lane >> 4;

  // XCD-aware swizzle: group (b,kvh) pinned to one XCD (2 groups/XCD)
  const int n   = blockIdx.y * 64 + blockIdx.x;   // grid (64, 16)
  const int x3  = n & 7, b1 = (n >> 3) & 1;
  const int pair = n >> 4;                        // 0..63
  const int grp  = x3 * 2 + b1;                   // 0..15 == b*8 + kvh
  const int b    = grp >> 3, kvh = grp & 7;
  const int head = kvh * 4 + wid;

  const int hi = 127 - pair, lo = pair;
  const int nt_hi = (hi >> 2) + 1;                // 17..32
  const int nt_lo = (lo >> 2) + 1;

  __shared__ bf16     Ks[2 * 64 * 64];   // [buf][hd-half][kv][32]
  __shared__ _Float16 Vs[2 * 64 * 64];   // [buf][tiled 4096]

  const int tb[2] = {hi * 16, lo * 16};

  bf16x8 qf[2][2];
#pragma unroll
  for (int tt = 0; tt < 2; ++tt) {
    const size_t qg = ((size_t)(b * S_ + tb[tt] + lm)) * (H_ * HD_) + head * HD_;
#pragma unroll
    for (int kf = 0; kf < 2; ++kf)
      qf[tt][kf] = *(const bf16x8*)&Q[qg + kf * 32 + quad * 8];
  }

  half4 onesh;
#pragma unroll
  for (int j = 0; j < 4; ++j) onesh[j] = (_Float16)1.0f;

  floatx4 o_acc[2][4] = {};
  floatx4 lacc[2] = {};

  const int tr = tid >> 2;          // staging row 0..63
  const int tc = (tid & 3) * 8;

  auto stage = [&](int t, int buf) {
#pragma unroll
    for (int c = 0; c < 2; ++c) {
      async16(&K[(size_t)(b * S_ + t * 64 + tr) * (HKV_ * HD_) + kvh * HD_ + c * 32 + tc],
              &Ks[buf * 4096 + c * 2048 + tid * 8]);
      async16(&VG[((size_t)(grp * 32 + t) << 12) + c * 2048 + tid * 8],
              &Vs[buf * 4096 + c * 2048 + tid * 8]);
    }
  };

  stage(0, 0);

  for (int t = 0; t < nt_hi; ++t) {
    const int cur = t & 1;
    asm volatile("s_waitcnt vmcnt(0)" ::: "memory");
    __syncthreads();
    if (t + 1 < nt_hi) stage(t + 1, cur ^ 1);

    const bf16*     Kb = &Ks[cur * 4096];
    const _Float16* Vb = &Vs[cur * 4096];
    const int t0 = t * 64;
    const int nact = (t < nt_lo) ? 2 : 1;

    int kcmax[2], kcross[2];
#pragma unroll
    for (int tt = 0; tt < 2; ++tt) {
      const int rel = tb[tt] + 15 - t0;
      kcmax[tt]  = (tt < nact) ? ((rel >> 4) >= 3 ? 4 : (rel >> 4) + 1) : 0;
      kcross[tt] = rel >> 4;
    }

    half4 pb[2][4];
#pragma unroll
    for (int kc = 0; kc < 4; ++kc) {
      if (kc >= kcmax[0]) break;   // kcmax[0] >= kcmax[1] always
      bf16x8 kb0 = *(const bf16x8*)&Kb[(kc * 16 + lm) * 32 + quad * 8];
      bf16x8 kb1 = *(const bf16x8*)&Kb[2048 + (kc * 16 + lm) * 32 + quad * 8];
#pragma unroll
      for (int tt = 0; tt < 2; ++tt) {
        if (kc >= kcmax[tt]) continue;
        floatx4 sT = {};
        sT = MFMA32B(kb0, qf[tt][0], sT);
        sT = MFMA32B(kb1, qf[tt][1], sT);
        half4 pk;
        if (kc == kcross[tt]) {
          const int qrel = tb[tt] + lm - t0;   // q - t0
#pragma unroll
          for (int r = 0; r < 4; ++r) {
            float p = (kc * 16 + quad * 4 + r > qrel) ? 0.f : EXP2(sT[r]);
            pk[r] = (_Float16)p;
          }
        } else {
#pragma unroll
          for (int r = 0; r < 4; ++r) pk[r] = (_Float16)EXP2(sT[r]);
        }
        pb[tt][kc] = pk;
      }
    }

    // row sums (unnormalized l) via ones-A MFMA
#pragma unroll
    for (int tt = 0; tt < 2; ++tt)
#pragma unroll
      for (int kc = 0; kc < 4; ++kc)
        if (kc < kcmax[tt]) lacc[tt] = MFMA16H(onesh, pb[tt][kc], lacc[tt]);

    // O^T += V^T * P^T
#pragma unroll
    for (int kc = 0; kc < 4; ++kc) {
      if (kc >= kcmax[0]) break;
#pragma unroll
      for (int nh = 0; nh < 4; ++nh) {
        half4 va = *(const half4*)&Vb[((kc * 4 + nh) * 4 + quad) * 64 + lm * 4];
#pragma unroll
        for (int tt = 0; tt < 2; ++tt)
          if (kc < kcmax[tt]) o_acc[tt][nh] = MFMA16H(va, pb[tt][kc], o_acc[tt][nh]);
      }
    }
  }

#pragma unroll
  for (int tt = 0; tt < 2; ++tt) {
    const float rl = 1.f / lacc[tt][0];
    const size_t rowg = (size_t)(b * S_ + tb[tt] + lm);
#pragma unroll
    for (int nh = 0; nh < 4; ++nh) {
      alignas(8) bf16 tmp[4];
#pragma unroll
      for (int r = 0; r < 4; ++r)
        tmp[r] = __float2bfloat16(o_acc[tt][nh][r] * rl);
      *(uint2*)&O[rowg * (H_ * HD_) + head * HD_ + nh * 16 + quad * 4] = *(uint2*)tmp;
    }
  }
}

// ---------------------------------------------------------------------------
extern "C" void kernel_launch(void* const* d_in, const int* in_sizes, int n_in,
                              void* d_out, int out_size, void* d_ws, size_t ws_size,
                              hipStream_t stream) {
  (void)in_sizes; (void)n_in; (void)out_size; (void)ws_size;
  const float* x  = (const float*)d_in[0];
  const float* wq = (const float*)d_in[1];
  const float* bq = (const float*)d_in[2];
  const float* wk = (const float*)d_in[3];
  const float* bk = (const float*)d_in[4];
  const float* wv = (const float*)d_in[5];
  const float* bv = (const float*)d_in[6];
  const float* wo = (const float*)d_in[7];
  const float* bo = (const float*)d_in[8];
  float* out = (float*)d_out;

  const int M = B_ * S_;        // 4096
  const int E = H_ * HD_;       // 2048
  const int EKV = HKV_ * HD_;   // 512

  char* ws = (char*)d_ws;
  size_t off = 0;
  auto alloc = [&](size_t bytes) {
    char* p = ws + off;
    off += (bytes + 255) & ~(size_t)255;
    return p;
  };
  bf16* xb  = (bf16*)alloc((size_t)M * D_ * 2);
  bf16* wqb = (bf16*)alloc((size_t)E * D_ * 2);
  bf16* wkb = (bf16*)alloc((size_t)EKV * D_ * 2);
  bf16* wvb = (bf16*)alloc((size_t)EKV * D_ * 2);
  bf16* wob = (bf16*)alloc((size_t)D_ * E * 2);
  bf16* Qb  = (bf16*)alloc((size_t)M * E * 2);
  bf16* Kb  = (bf16*)alloc((size_t)M * EKV * 2);
  _Float16* VG = (_Float16*)alloc((size_t)M * EKV * 2);  // tiled V, f16
  bf16* Ob  = (bf16*)alloc((size_t)M * E * 2);

  f2b_all<<<9216, 256, 0, stream>>>(x, wq, wk, wv, wo, xb, wqb, wkb, wvb, wob);

  gemm_qkv<<<dim3(24, M / 128), 256, 0, stream>>>(xb, wqb, wkb, wvb, bq, bk, bv,
                                                  Qb, Kb, VG);

  attn_kernel<<<dim3(64, 16), 256, 0, stream>>>(Qb, Kb, VG, Ob);

  gemm_o<<<dim3(D_ / 128, M / 128), 256, 0, stream>>>(Ob, wob, bo, out, D_, D_);
}

// Round 6
// 295.258 us; speedup vs baseline: 1.7856x; 1.0185x over previous
//
#include <hip/hip_runtime.h>
#include <hip/hip_bf16.h>
#include <cmath>

#define B_   2
#define S_   2048
#define D_   2048
#define H_   32
#define HKV_ 8
#define HD_  64
// G = H/HKV = 4

using bf16 = __hip_bfloat16;
typedef __bf16    bf16x8 __attribute__((ext_vector_type(8)));
typedef float     floatx4 __attribute__((ext_vector_type(4)));
typedef _Float16  half4 __attribute__((ext_vector_type(4)));

#if __has_builtin(__builtin_amdgcn_exp2f)
#define EXP2(x) __builtin_amdgcn_exp2f(x)
#else
#define EXP2(x) exp2f(x)
#endif

#define QSCALE 0.18033688011112042f   // 0.125 * log2(e)

__device__ inline void async16(const void* g, void* l) {
  __builtin_amdgcn_global_load_lds(
      (const __attribute__((address_space(1))) void*)g,
      (__attribute__((address_space(3))) void*)l, 16, 0, 0);
}

#define MFMA32B(a, b, c) __builtin_amdgcn_mfma_f32_16x16x32_bf16((a), (b), (c), 0, 0, 0)
#define MFMA16H(a, b, c) __builtin_amdgcn_mfma_f32_16x16x16f16((a), (b), (c), 0, 0, 0)

// ---------- fused fp32->bf16 conversion for all 5 tensors (wq pre-scaled) ---
// chunk sizes (8-elem units): x 1048576 | wq 524288 | wk 131072 | wv 131072 | wo 524288
__global__ void f2b_all(const float* __restrict__ x,  const float* __restrict__ wq,
                        const float* __restrict__ wk, const float* __restrict__ wv,
                        const float* __restrict__ wo,
                        bf16* __restrict__ xb,  bf16* __restrict__ wqb,
                        bf16* __restrict__ wkb, bf16* __restrict__ wvb,
                        bf16* __restrict__ wob) {
  const int i = blockIdx.x * blockDim.x + threadIdx.x;
  const float* src; bf16* dst; int off; float scale = 1.0f;
  if (i < 1048576)      { src = x;  dst = xb;  off = 0; }
  else if (i < 1572864) { src = wq; dst = wqb; off = 1048576; scale = QSCALE; }
  else if (i < 1703936) { src = wk; dst = wkb; off = 1572864; }
  else if (i < 1835008) { src = wv; dst = wvb; off = 1703936; }
  else                  { src = wo; dst = wob; off = 1835008; }
  const int j = i - off;
  float4 a  = ((const float4*)src)[2 * j];
  float4 b2 = ((const float4*)src)[2 * j + 1];
  alignas(16) bf16 t[8];
  t[0] = __float2bfloat16(a.x * scale);  t[1] = __float2bfloat16(a.y * scale);
  t[2] = __float2bfloat16(a.z * scale);  t[3] = __float2bfloat16(a.w * scale);
  t[4] = __float2bfloat16(b2.x * scale); t[5] = __float2bfloat16(b2.y * scale);
  t[6] = __float2bfloat16(b2.z * scale); t[7] = __float2bfloat16(b2.w * scale);
  ((uint4*)dst)[j] = *(const uint4*)t;
}

// -------------------- shared GEMM tile body: C = A * B^T + bias*bscale ------
// MODE 0: bf16 row-major (swapped MFMA -> packed 8B stores)
// MODE 1: f32 row-major  (swapped MFMA -> float4 stores)
// MODE 2: f16 V-tiled layout (original order -> packed 8B stores, j==r contig)
template <int MODE, typename OutT>
__device__ inline void gemm_body(const bf16* __restrict__ Ag, const bf16* __restrict__ Bg,
                                 const float* __restrict__ bias, float bscale,
                                 OutT* __restrict__ C, int Ncol, int K, int bm, int colb,
                                 bf16* As, bf16* Bs) {
  const int tid  = threadIdx.x;
  const int wid  = tid >> 6, lane = tid & 63;
  const int lm   = lane & 15, quad = lane >> 4;
  const int wm   = (wid >> 1) * 64, wn = (wid & 1) * 64;

  floatx4 acc[4][4] = {};

  const int l0 = tid * 8;
  const int r0 = l0 >> 5, c0 = l0 & 31;
  const int r1 = r0 + 64;

  for (int k0 = 0; k0 < K; k0 += 32) {
    async16(Ag + (size_t)r0 * K + k0 + c0, &As[l0]);
    async16(Ag + (size_t)r1 * K + k0 + c0, &As[l0 + 2048]);
    async16(Bg + (size_t)r0 * K + k0 + c0, &Bs[l0]);
    async16(Bg + (size_t)r1 * K + k0 + c0, &Bs[l0 + 2048]);
    asm volatile("s_waitcnt vmcnt(0)" ::: "memory");
    __syncthreads();

    bf16x8 aF[4], bF[4];
#pragma unroll
    for (int mi = 0; mi < 4; ++mi)
      aF[mi] = *(const bf16x8*)&As[(wm + mi * 16 + lm) * 32 + quad * 8];
#pragma unroll
    for (int ni = 0; ni < 4; ++ni)
      bF[ni] = *(const bf16x8*)&Bs[(wn + ni * 16 + lm) * 32 + quad * 8];
#pragma unroll
    for (int mi = 0; mi < 4; ++mi)
#pragma unroll
      for (int ni = 0; ni < 4; ++ni) {
        if constexpr (MODE == 2)
          acc[mi][ni] = MFMA32B(aF[mi], bF[ni], acc[mi][ni]);
        else
          acc[mi][ni] = MFMA32B(bF[ni], aF[mi], acc[mi][ni]);  // swapped: D^T
      }
    __syncthreads();
  }

  if constexpr (MODE != 2) {
    // swapped layout: lane holds row m = ..+lm, cols n = col0..col0+3
#pragma unroll
    for (int mi = 0; mi < 4; ++mi) {
      const int row = bm * 128 + wm + mi * 16 + lm;
#pragma unroll
      for (int ni = 0; ni < 4; ++ni) {
        const int col0 = colb + wn + ni * 16 + quad * 4;
        float4 bv4 = *(const float4*)&bias[col0];
        if constexpr (MODE == 0) {
          alignas(8) bf16 t4[4];
#pragma unroll
          for (int r = 0; r < 4; ++r)
            t4[r] = __float2bfloat16(acc[mi][ni][r] + ((const float*)&bv4)[r] * bscale);
          *(uint2*)&((bf16*)C)[(size_t)row * Ncol + col0] = *(const uint2*)t4;
        } else {
          float4 o4;
          o4.x = acc[mi][ni][0] + bv4.x; o4.y = acc[mi][ni][1] + bv4.y;
          o4.z = acc[mi][ni][2] + bv4.z; o4.w = acc[mi][ni][3] + bv4.w;
          *(float4*)&((float*)C)[(size_t)row * Ncol + col0] = o4;
        }
      }
    }
  } else {
    // V tiled: per (b,kvh), 32 tiles of 64kv x 64hd, [kc][nh][qd][lmw][j];
    // lane's 4 r-values are j=0..3 contiguous.
#pragma unroll
    for (int mi = 0; mi < 4; ++mi) {
      const int rowg = bm * 128 + wm + mi * 16 + quad * 4;   // %4 == 0
      const int b    = rowg >> 11, s = rowg & 2047;
      const int tile = s >> 6, kvin = s & 63;
      const int kc = kvin >> 4, qd = (kvin >> 2) & 3;
#pragma unroll
      for (int ni = 0; ni < 4; ++ni) {
        const int col = colb + wn + ni * 16 + lm;            // 0..511
        const float bv = bias[col];
        const int kvh = col >> 6, hd = col & 63;
        const int nh = hd >> 4, lmw = hd & 15;
        const size_t base = ((size_t)((b * 8 + kvh) * 32 + tile) << 12) +
                            (((kc * 4 + nh) * 4 + qd) << 6) + (lmw << 2);
        alignas(8) _Float16 t4[4];
#pragma unroll
        for (int r = 0; r < 4; ++r)
          t4[r] = (_Float16)(acc[mi][ni][r] + bv);
        *(uint2*)&((_Float16*)C)[base] = *(const uint2*)t4;
      }
    }
  }
}

// Fused QKV projection: grid.x 0..23 -> Q(16, pre-scaled) | K(4) | V(4, tiled f16)
__global__ __launch_bounds__(256, 2)
void gemm_qkv(const bf16* __restrict__ xb,
              const bf16* __restrict__ wq, const bf16* __restrict__ wk,
              const bf16* __restrict__ wv,
              const float* __restrict__ bq, const float* __restrict__ bk,
              const float* __restrict__ bv,
              bf16* __restrict__ Qo, bf16* __restrict__ Ko, _Float16* __restrict__ VG) {
  __shared__ bf16 As[128 * 32];
  __shared__ bf16 Bs[128 * 32];
  const int bn = blockIdx.x, bm = blockIdx.y;
  const int K = D_;
  if (bn < 16) {
    gemm_body<0, bf16>(xb + (size_t)bm * 128 * K, wq + (size_t)(bn * 128) * K, bq, QSCALE,
                       Qo, H_ * HD_, K, bm, bn * 128, As, Bs);
  } else if (bn < 20) {
    gemm_body<0, bf16>(xb + (size_t)bm * 128 * K, wk + (size_t)((bn - 16) * 128) * K, bk, 1.0f,
                       Ko, HKV_ * HD_, K, bm, (bn - 16) * 128, As, Bs);
  } else {
    gemm_body<2, _Float16>(xb + (size_t)bm * 128 * K, wv + (size_t)((bn - 20) * 128) * K, bv, 1.0f,
                           VG, HKV_ * HD_, K, bm, (bn - 20) * 128, As, Bs);
  }
}

// Plain GEMM (O-projection): C fp32 = A * B^T + bias
__global__ __launch_bounds__(256, 2)
void gemm_o(const bf16* __restrict__ A, const bf16* __restrict__ Bm,
            const float* __restrict__ bias, float* __restrict__ C,
            int Ncol, int K) {
  __shared__ bf16 As[128 * 32];
  __shared__ bf16 Bs[128 * 32];
  const int bn = blockIdx.x, bm = blockIdx.y;
  gemm_body<1, float>(A + (size_t)bm * 128 * K, Bm + (size_t)bn * 128 * K, bias, 1.0f,
                      C, Ncol, K, bm, bn * 128, As, Bs);
}

// -------------------- causal GQA flash attention, v5 ------------------------
// Block = (pair, b, kvh): 4 waves = 4 heads of one GQA group sharing K/V LDS.
// Each wave owns two 16-row q-tiles (hi=127-pair, lo=pair), interleaved kv-loop.
// P register-resident; l-sum via single ones-MFMA on VALU-presummed P chunks.
__global__ __launch_bounds__(256, 4)
void attn_kernel(const bf16* __restrict__ Q, const bf16* __restrict__ K,
                 const _Float16* __restrict__ VG, bf16* __restrict__ O) {
  const int tid = threadIdx.x;
  const int wid = tid >> 6, lane = tid & 63;
  const int lm = lane & 15, quad = lane >> 4;

  // XCD-aware swizzle: group (b,kvh) pinned to one XCD (2 groups/XCD)
  const int n   = blockIdx.y * 64 + blockIdx.x;   // grid (64, 16)
  const int x3  = n & 7, b1 = (n >> 3) & 1;
  const int pair = n >> 4;                        // 0..63
  const int grp  = x3 * 2 + b1;                   // 0..15 == b*8 + kvh
  const int b    = grp >> 3, kvh = grp & 7;
  const int head = kvh * 4 + wid;

  const int hi = 127 - pair, lo = pair;
  const int nt_hi = (hi >> 2) + 1;                // 17..32
  const int nt_lo = (lo >> 2) + 1;

  __shared__ bf16     Ks[2 * 64 * 64];   // [buf][hd-half][kv][32]
  __shared__ _Float16 Vs[2 * 64 * 64];   // [buf][tiled 4096]

  const int tb[2] = {hi * 16, lo * 16};

  bf16x8 qf[2][2];
#pragma unroll
  for (int tt = 0; tt < 2; ++tt) {
    const size_t qg = ((size_t)(b * S_ + tb[tt] + lm)) * (H_ * HD_) + head * HD_;
#pragma unroll
    for (int kf = 0; kf < 2; ++kf)
      qf[tt][kf] = *(const bf16x8*)&Q[qg + kf * 32 + quad * 8];
  }

  half4 onesh;
#pragma unroll
  for (int j = 0; j < 4; ++j) onesh[j] = (_Float16)1.0f;

  floatx4 o_acc[2][4] = {};
  floatx4 lacc[2] = {};

  const int tr = tid >> 2;          // staging row 0..63
  const int tc = (tid & 3) * 8;

  auto stage = [&](int t, int buf) {
#pragma unroll
    for (int c = 0; c < 2; ++c) {
      async16(&K[(size_t)(b * S_ + t * 64 + tr) * (HKV_ * HD_) + kvh * HD_ + c * 32 + tc],
              &Ks[buf * 4096 + c * 2048 + tid * 8]);
      async16(&VG[((size_t)(grp * 32 + t) << 12) + c * 2048 + tid * 8],
              &Vs[buf * 4096 + c * 2048 + tid * 8]);
    }
  };

  stage(0, 0);

  for (int t = 0; t < nt_hi; ++t) {
    const int cur = t & 1;
    asm volatile("s_waitcnt vmcnt(0)" ::: "memory");
    __syncthreads();
    if (t + 1 < nt_hi) stage(t + 1, cur ^ 1);

    const bf16*     Kb = &Ks[cur * 4096];
    const _Float16* Vb = &Vs[cur * 4096];
    const int t0 = t * 64;
    const int nact = (t < nt_lo) ? 2 : 1;

    int kcmax[2], kcross[2];
#pragma unroll
    for (int tt = 0; tt < 2; ++tt) {
      const int rel = tb[tt] + 15 - t0;
      kcmax[tt]  = (tt < nact) ? ((rel >> 4) >= 3 ? 4 : (rel >> 4) + 1) : 0;
      kcross[tt] = rel >> 4;
    }

    half4 pb[2][4];
#pragma unroll
    for (int kc = 0; kc < 4; ++kc) {
      if (kc >= kcmax[0]) break;   // kcmax[0] >= kcmax[1] always
      bf16x8 kb0 = *(const bf16x8*)&Kb[(kc * 16 + lm) * 32 + quad * 8];
      bf16x8 kb1 = *(const bf16x8*)&Kb[2048 + (kc * 16 + lm) * 32 + quad * 8];
#pragma unroll
      for (int tt = 0; tt < 2; ++tt) {
        if (kc >= kcmax[tt]) continue;
        floatx4 sT = {};
        sT = MFMA32B(kb0, qf[tt][0], sT);
        sT = MFMA32B(kb1, qf[tt][1], sT);
        half4 pk;
        if (kc == kcross[tt]) {
          const int qrel = tb[tt] + lm - t0;   // q - t0
#pragma unroll
          for (int r = 0; r < 4; ++r) {
            float p = (kc * 16 + quad * 4 + r > qrel) ? 0.f : EXP2(sT[r]);
            pk[r] = (_Float16)p;
          }
        } else {
#pragma unroll
          for (int r = 0; r < 4; ++r) pk[r] = (_Float16)EXP2(sT[r]);
        }
        pb[tt][kc] = pk;
      }
    }

    // row sums: presum chunks in f16 VALU, one ones-MFMA per tile
#pragma unroll
    for (int tt = 0; tt < 2; ++tt) {
      if (kcmax[tt] == 0) continue;
      half4 ps = pb[tt][0];
      if (kcmax[tt] > 1) ps += pb[tt][1];
      if (kcmax[tt] > 2) ps += pb[tt][2];
      if (kcmax[tt] > 3) ps += pb[tt][3];
      lacc[tt] = MFMA16H(onesh, ps, lacc[tt]);
    }

    // O^T += V^T * P^T
#pragma unroll
    for (int kc = 0; kc < 4; ++kc) {
      if (kc >= kcmax[0]) break;
#pragma unroll
      for (int nh = 0; nh < 4; ++nh) {
        half4 va = *(const half4*)&Vb[((kc * 4 + nh) * 4 + quad) * 64 + lm * 4];
#pragma unroll
        for (int tt = 0; tt < 2; ++tt)
          if (kc < kcmax[tt]) o_acc[tt][nh] = MFMA16H(va, pb[tt][kc], o_acc[tt][nh]);
      }
    }
  }

#pragma unroll
  for (int tt = 0; tt < 2; ++tt) {
    const float rl = 1.f / lacc[tt][0];
    const size_t rowg = (size_t)(b * S_ + tb[tt] + lm);
#pragma unroll
    for (int nh = 0; nh < 4; ++nh) {
      alignas(8) bf16 tmp[4];
#pragma unroll
      for (int r = 0; r < 4; ++r)
        tmp[r] = __float2bfloat16(o_acc[tt][nh][r] * rl);
      *(uint2*)&O[rowg * (H_ * HD_) + head * HD_ + nh * 16 + quad * 4] = *(uint2*)tmp;
    }
  }
}

// ---------------------------------------------------------------------------
extern "C" void kernel_launch(void* const* d_in, const int* in_sizes, int n_in,
                              void* d_out, int out_size, void* d_ws, size_t ws_size,
                              hipStream_t stream) {
  (void)in_sizes; (void)n_in; (void)out_size; (void)ws_size;
  const float* x  = (const float*)d_in[0];
  const float* wq = (const float*)d_in[1];
  const float* bq = (const float*)d_in[2];
  const float* wk = (const float*)d_in[3];
  const float* bk = (const float*)d_in[4];
  const float* wv = (const float*)d_in[5];
  const float* bv = (const float*)d_in[6];
  const float* wo = (const float*)d_in[7];
  const float* bo = (const float*)d_in[8];
  float* out = (float*)d_out;

  const int M = B_ * S_;        // 4096
  const int E = H_ * HD_;       // 2048
  const int EKV = HKV_ * HD_;   // 512

  char* ws = (char*)d_ws;
  size_t off = 0;
  auto alloc = [&](size_t bytes) {
    char* p = ws + off;
    off += (bytes + 255) & ~(size_t)255;
    return p;
  };
  bf16* xb  = (bf16*)alloc((size_t)M * D_ * 2);
  bf16* wqb = (bf16*)alloc((size_t)E * D_ * 2);
  bf16* wkb = (bf16*)alloc((size_t)EKV * D_ * 2);
  bf16* wvb = (bf16*)alloc((size_t)EKV * D_ * 2);
  bf16* wob = (bf16*)alloc((size_t)D_ * E * 2);
  bf16* Qb  = (bf16*)alloc((size_t)M * E * 2);
  bf16* Kb  = (bf16*)alloc((size_t)M * EKV * 2);
  _Float16* VG = (_Float16*)alloc((size_t)M * EKV * 2);  // tiled V, f16
  bf16* Ob  = (bf16*)alloc((size_t)M * E * 2);

  f2b_all<<<9216, 256, 0, stream>>>(x, wq, wk, wv, wo, xb, wqb, wkb, wvb, wob);

  gemm_qkv<<<dim3(24, M / 128), 256, 0, stream>>>(xb, wqb, wkb, wvb, bq, bk, bv,
                                                  Qb, Kb, VG);

  attn_kernel<<<dim3(64, 16), 256, 0, stream>>>(Qb, Kb, VG, Ob);

  gemm_o<<<dim3(D_ / 128, M / 128), 256, 0, stream>>>(Ob, wob, bo, out, D_, D_);
}